// Round 7
// baseline (543.327 us; speedup 1.0000x reference)
//
#include <hip/hip_runtime.h>

#define B_   2
#define S_   2048
#define D_   2048
#define H_   16
#define HD_  128
#define WIN_ 256
#define M_   (B_ * S_)  // 4096

typedef float  f32x4  __attribute__((ext_vector_type(4)));
typedef short  s16x8  __attribute__((ext_vector_type(8)));
typedef __bf16 bf16x8 __attribute__((ext_vector_type(8)));
typedef unsigned short ushort_t;

__device__ inline unsigned short f2b(float f) {
  unsigned u = __builtin_bit_cast(unsigned, f);
  u += 0x7fffu + ((u >> 16) & 1u);  // RNE
  return (unsigned short)(u >> 16);
}
__device__ inline float b2f(unsigned short h) {
  unsigned u = ((unsigned)h) << 16;
  return __builtin_bit_cast(float, u);
}

// Hedged MFMA call: gfx950 builtin may take v8bf16 (upstream clang) or v8i16.
template <typename T>
__device__ auto mfma_impl(T a, T b, f32x4 c, int)
    -> decltype(__builtin_amdgcn_mfma_f32_16x16x32_bf16(a, b, c, 0, 0, 0)) {
  return __builtin_amdgcn_mfma_f32_16x16x32_bf16(a, b, c, 0, 0, 0);
}
template <typename T>
__device__ f32x4 mfma_impl(T a, T b, f32x4 c, long) {
  return __builtin_amdgcn_mfma_f32_16x16x32_bf16(
      __builtin_bit_cast(bf16x8, a), __builtin_bit_cast(bf16x8, b), c, 0, 0, 0);
}
__device__ inline f32x4 mfma_bf16(s16x8 a, s16x8 b, f32x4 c) {
  return mfma_impl(a, b, c, 0);
}

// ---- async global->LDS, 16B/lane. lds base must be wave-uniform; lane i lands at +i*16B.
#if defined(__has_builtin)
#if __has_builtin(__builtin_amdgcn_global_load_lds)
#define HAS_GLL 1
#endif
#endif
#ifndef HAS_GLL
#define HAS_GLL 0
#endif

__device__ inline void gl_lds16(const ushort_t* g, ushort_t* lds_wave_base) {
#if HAS_GLL
  __builtin_amdgcn_global_load_lds(
      (const __attribute__((address_space(1))) unsigned int*)g,
      (__attribute__((address_space(3))) unsigned int*)lds_wave_base, 16, 0, 0);
#else
  const int lane = threadIdx.x & 63;
  *(uint4*)(lds_wave_base + lane * 8) = *(const uint4*)g;
#endif
}

// ---------------- split f32 -> bf16 hi + lo ----------------
__global__ __launch_bounds__(256) void k_split(const float* __restrict__ x,
                                               ushort_t* __restrict__ hi,
                                               ushort_t* __restrict__ lo, int n) {
  int i = (blockIdx.x * 256 + threadIdx.x) * 4;
  if (i + 3 < n) {
    float4 v = *(const float4*)(x + i);
    ushort4 h, l;
    h.x = f2b(v.x); l.x = f2b(v.x - b2f(h.x));
    h.y = f2b(v.y); l.y = f2b(v.y - b2f(h.y));
    h.z = f2b(v.z); l.z = f2b(v.z - b2f(h.z));
    h.w = f2b(v.w); l.w = f2b(v.w - b2f(h.w));
    *(ushort4*)(hi + i) = h;
    *(ushort4*)(lo + i) = l;
  }
}

// ---------------- fused transpose + split of all 4 weights: z picks W ----------------
// WT[n][k] = W[k][n]; lo written only where needed (Wq, Wk).
__global__ __launch_bounds__(256) void k_transpose4(const float* __restrict__ W0,
                                                    const float* __restrict__ W1,
                                                    const float* __restrict__ W2,
                                                    const float* __restrict__ W3,
                                                    ushort_t* __restrict__ T0h,
                                                    ushort_t* __restrict__ T0l,
                                                    ushort_t* __restrict__ T1h,
                                                    ushort_t* __restrict__ T1l,
                                                    ushort_t* __restrict__ T2h,
                                                    ushort_t* __restrict__ T3h) {
  __shared__ float t[32][33];
  const int z = blockIdx.z;
  const float* W = (z == 0) ? W0 : (z == 1) ? W1 : (z == 2) ? W2 : W3;
  ushort_t* Th = (z == 0) ? T0h : (z == 1) ? T1h : (z == 2) ? T2h : T3h;
  ushort_t* Tl = (z == 0) ? T0l : (z == 1) ? T1l : nullptr;
  int bx = blockIdx.x * 32, by = blockIdx.y * 32;
  int tx = threadIdx.x, ty = threadIdx.y;  // 32 x 8
#pragma unroll
  for (int r = 0; r < 32; r += 8)
    t[ty + r][tx] = W[(size_t)(by + ty + r) * D_ + bx + tx];
  __syncthreads();
#pragma unroll
  for (int r = 0; r < 32; r += 8) {
    float v = t[tx][ty + r];
    unsigned short h = f2b(v);
    Th[(size_t)(bx + ty + r) * D_ + by + tx] = h;
    if (Tl) Tl[(size_t)(bx + ty + r) * D_ + by + tx] = f2b(v - b2f(h));
  }
}

// ---------------- bf16 transpose for V: Vt[b*D + c][s] = Vb[b*S + s][c] ----------------
__global__ __launch_bounds__(256) void k_vtrans(const ushort_t* __restrict__ Vb,
                                                ushort_t* __restrict__ Vt) {
  __shared__ ushort_t t[32][33];
  int bx = blockIdx.x * 32, by = blockIdx.y * 32, b = blockIdx.z;
  int tx = threadIdx.x, ty = threadIdx.y;  // 32 x 8
#pragma unroll
  for (int r = 0; r < 32; r += 8)
    t[ty + r][tx] = Vb[((size_t)(b * S_ + by + ty + r)) * D_ + bx + tx];
  __syncthreads();
#pragma unroll
  for (int r = 0; r < 32; r += 8)
    Vt[((size_t)(b * D_ + bx + ty + r)) * S_ + by + tx] = t[tx][ty + r];
}

// ---------------- m97-structure MFMA GEMM: C = A[MxK] * Bt[NxK]^T ----------------
// 128x128 tile, BK=32, global_load_lds width-16 staging, 4 waves 2x2, 4x4 acc/wave.
// SPLIT3: A,B have hi/lo pairs, 3 MFMAs (hh,hl,lh). OUT: 0=bf16, 1=bf16 hi/lo, 2=f32+bias.
template <bool SPLIT3, int OUT>
__global__ __launch_bounds__(256) void k_gemm(const ushort_t* __restrict__ Ah,
                                              const ushort_t* __restrict__ Al,
                                              const ushort_t* __restrict__ Bh,
                                              const ushort_t* __restrict__ Bl,
                                              ushort_t* __restrict__ Co,
                                              ushort_t* __restrict__ Col,
                                              float* __restrict__ Cf,
                                              const float* __restrict__ bias,
                                              int M, int N, int K) {
  constexpr int NB = SPLIT3 ? 2 : 1;
  __shared__ ushort_t Ash[NB][128][32];  // unpadded: layout forced by global_load_lds
  __shared__ ushort_t Bsh[NB][128][32];
  const int tid = threadIdx.x;
  const int wave = tid >> 6, lane = tid & 63;
  const int m0 = blockIdx.y * 128, n0 = blockIdx.x * 128;
  const int wr = (wave >> 1) * 64, wc = (wave & 1) * 64;
  const int quad = lane >> 4, l16 = lane & 15;
  const int srow = tid >> 2, scol = (tid & 3) * 8;
  const size_t aoff = (size_t)(m0 + srow) * K + scol;
  const size_t boff = (size_t)(n0 + srow) * K + scol;
  const int wofs = wave * 512;  // ushort offset of this wave's 1KB chunk

  f32x4 acc[4][4] = {};
  for (int k0 = 0; k0 < K; k0 += 32) {
#pragma unroll
    for (int s = 0; s < NB; s++) {
      const ushort_t* Asrc = (SPLIT3 && s) ? (Al + aoff + k0) : (Ah + aoff + k0);
      const ushort_t* Bsrc = (SPLIT3 && s) ? (Bl + boff + k0) : (Bh + boff + k0);
      gl_lds16(Asrc,                 &Ash[s][0][0] + wofs);
      gl_lds16(Asrc + (size_t)64 * K, &Ash[s][64][0] + wofs);
      gl_lds16(Bsrc,                 &Bsh[s][0][0] + wofs);
      gl_lds16(Bsrc + (size_t)64 * K, &Bsh[s][64][0] + wofs);
    }
    __syncthreads();
    s16x8 bf[NB][4];
#pragma unroll
    for (int s = 0; s < NB; s++)
#pragma unroll
      for (int jt = 0; jt < 4; jt++)
        bf[s][jt] = *(const s16x8*)&Bsh[s][wc + jt * 16 + l16][quad * 8];
#pragma unroll
    for (int it = 0; it < 4; it++) {
      s16x8 ah = *(const s16x8*)&Ash[0][wr + it * 16 + l16][quad * 8];
      s16x8 al;
      if (SPLIT3) al = *(const s16x8*)&Ash[NB - 1][wr + it * 16 + l16][quad * 8];
#pragma unroll
      for (int jt = 0; jt < 4; jt++) {
        acc[it][jt] = mfma_bf16(ah, bf[0][jt], acc[it][jt]);
        if (SPLIT3) {
          acc[it][jt] = mfma_bf16(ah, bf[NB - 1][jt], acc[it][jt]);
          acc[it][jt] = mfma_bf16(al, bf[0][jt], acc[it][jt]);
        }
      }
    }
    __syncthreads();
  }
#pragma unroll
  for (int it = 0; it < 4; it++)
#pragma unroll
    for (int jt = 0; jt < 4; jt++)
#pragma unroll
      for (int r = 0; r < 4; r++) {
        int row = m0 + wr + it * 16 + quad * 4 + r;
        int col = n0 + wc + jt * 16 + l16;
        float v = acc[it][jt][r];
        if (OUT == 2) {
          Cf[(size_t)row * N + col] = v + bias[col];
        } else if (OUT == 1) {
          unsigned short h = f2b(v);
          Co[(size_t)row * N + col]  = h;
          Col[(size_t)row * N + col] = f2b(v - b2f(h));
        } else {
          Co[(size_t)row * N + col] = f2b(v);
        }
      }
}

// ---------------- MFMA flash attention, 64-query tile per block (R3-proven) ----------------
// Scores: split-3 bf16 QK^T. P,V: plain bf16. Online softmax.
// grid: (S/64, H, B); 256 threads = 4 waves, wave w owns queries w*16..w*16+15.
__global__ __launch_bounds__(256) void k_fattn(const ushort_t* __restrict__ Qh,
                                               const ushort_t* __restrict__ Ql,
                                               const ushort_t* __restrict__ Kh,
                                               const ushort_t* __restrict__ Kl,
                                               const ushort_t* __restrict__ Vt,
                                               const int* __restrict__ amask,
                                               ushort_t* __restrict__ AO) {
  __shared__ ushort_t Ksh[64][136];   // [key][dim], +8 pad
  __shared__ ushort_t Ksl[64][136];
  __shared__ ushort_t Vs[128][72];    // [hd][key], +8 pad
  __shared__ ushort_t ps[4][16][72];  // per-wave P scratch [q][key]
  __shared__ int ams[320];
  const int tid = threadIdx.x;
  const int wave = tid >> 6, lane = tid & 63;
  const int quad = lane >> 4, l16 = lane & 15;
  const int qt = blockIdx.x, h = blockIdx.y, b = blockIdx.z;
  const int q0 = qt * 64;

  for (int x = tid; x < 320; x += 256) {
    int j = q0 - 256 + x;
    ams[x] = (j >= 0) ? amask[b * S_ + j] : 0;
  }

  const int qrowA = q0 + wave * 16 + l16;
  const ushort_t* qbh = Qh + ((size_t)(b * S_ + qrowA) * D_) + h * HD_;
  const ushort_t* qbl = Ql + ((size_t)(b * S_ + qrowA) * D_) + h * HD_;
  s16x8 qh[4], ql[4];
#pragma unroll
  for (int kk = 0; kk < 4; kk++) {
    qh[kk] = *(const s16x8*)(qbh + kk * 32 + quad * 8);
    ql[kk] = *(const s16x8*)(qbl + kk * 32 + quad * 8);
  }

  f32x4 O[8] = {};
  float m_run[4], l_run[4];
#pragma unroll
  for (int r = 0; r < 4; r++) { m_run[r] = -3.0e38f; l_run[r] = 0.f; }

  const int t0 = (qt < 4) ? (4 - qt) : 0;  // kb = 64*(qt+t-4) >= 0
  for (int t = t0; t < 5; t++) {
    const int kb = q0 - 256 + 64 * t;
    __syncthreads();
    // stage K tile hi/lo: [key][dim]; thread: key=tid>>2, dims (tid&3)*32..+31
    {
      const int key = tid >> 2, dimb = (tid & 3) * 32;
      const ushort_t* kgh = Kh + ((size_t)(b * S_ + kb + key) * D_) + h * HD_ + dimb;
      const ushort_t* kgl = Kl + ((size_t)(b * S_ + kb + key) * D_) + h * HD_ + dimb;
#pragma unroll
      for (int u = 0; u < 4; u++) {
        *(uint4*)&Ksh[key][dimb + u * 8] = *(const uint4*)(kgh + u * 8);
        *(uint4*)&Ksl[key][dimb + u * 8] = *(const uint4*)(kgl + u * 8);
      }
      // stage V tile (pre-transposed): Vs[hd][key]; thread: hd=tid>>1, keys (tid&1)*32..+31
      const int hd = tid >> 1, keyb = (tid & 1) * 32;
      const ushort_t* vg = Vt + ((size_t)(b * D_ + h * HD_ + hd) * S_) + kb + keyb;
#pragma unroll
      for (int u = 0; u < 4; u++)
        *(uint4*)&Vs[hd][keyb + u * 8] = *(const uint4*)(vg + u * 8);
    }
    __syncthreads();

    f32x4 sacc[4] = {};
#pragma unroll
    for (int kk = 0; kk < 4; kk++)
#pragma unroll
      for (int nt = 0; nt < 4; nt++) {
        s16x8 kfh = *(const s16x8*)&Ksh[nt * 16 + l16][kk * 32 + quad * 8];
        s16x8 kfl = *(const s16x8*)&Ksl[nt * 16 + l16][kk * 32 + quad * 8];
        sacc[nt] = mfma_bf16(qh[kk], kfh, sacc[nt]);
        sacc[nt] = mfma_bf16(qh[kk], kfl, sacc[nt]);
        sacc[nt] = mfma_bf16(ql[kk], kfh, sacc[nt]);
      }

#pragma unroll
    for (int nt = 0; nt < 4; nt++) {
      const int j = kb + nt * 16 + l16;
      const bool amok = ams[64 * t + nt * 16 + l16] != 0;
#pragma unroll
      for (int r = 0; r < 4; r++) {
        const int iq = q0 + wave * 16 + quad * 4 + r;
        const bool ok = amok && (j <= iq) && (j > iq - WIN_);
        if (!ok) sacc[nt][r] = -3.0e38f;
      }
    }
    float mt[4];
#pragma unroll
    for (int r = 0; r < 4; r++) {
      mt[r] = fmaxf(fmaxf(sacc[0][r], sacc[1][r]), fmaxf(sacc[2][r], sacc[3][r]));
      mt[r] = fmaxf(mt[r], __shfl_xor(mt[r], 1));
      mt[r] = fmaxf(mt[r], __shfl_xor(mt[r], 2));
      mt[r] = fmaxf(mt[r], __shfl_xor(mt[r], 4));
      mt[r] = fmaxf(mt[r], __shfl_xor(mt[r], 8));
    }
    float alpha[4], lt[4];
#pragma unroll
    for (int r = 0; r < 4; r++) {
      float mnew = fmaxf(m_run[r], mt[r]);
      alpha[r] = __expf(m_run[r] - mnew);
      m_run[r] = mnew;
      lt[r] = 0.f;
#pragma unroll
      for (int nt = 0; nt < 4; nt++) {
        float s = sacc[nt][r];
        float p = (s > -1.0e30f) ? __expf(s - mnew) : 0.f;
        sacc[nt][r] = p;
        lt[r] += p;
      }
      lt[r] += __shfl_xor(lt[r], 1);
      lt[r] += __shfl_xor(lt[r], 2);
      lt[r] += __shfl_xor(lt[r], 4);
      lt[r] += __shfl_xor(lt[r], 8);
      l_run[r] = l_run[r] * alpha[r] + lt[r];
    }
#pragma unroll
    for (int o = 0; o < 8; o++)
#pragma unroll
      for (int r = 0; r < 4; r++) O[o][r] *= alpha[r];
#pragma unroll
    for (int nt = 0; nt < 4; nt++)
#pragma unroll
      for (int r = 0; r < 4; r++)
        ps[wave][quad * 4 + r][nt * 16 + l16] = f2b(sacc[nt][r]);
    __syncthreads();
#pragma unroll
    for (int kk2 = 0; kk2 < 2; kk2++) {
      s16x8 pf = *(const s16x8*)&ps[wave][l16][kk2 * 32 + quad * 8];
#pragma unroll
      for (int o = 0; o < 8; o++) {
        s16x8 vf = *(const s16x8*)&Vs[o * 16 + l16][kk2 * 32 + quad * 8];
        O[o] = mfma_bf16(pf, vf, O[o]);
      }
    }
  }
#pragma unroll
  for (int r = 0; r < 4; r++) l_run[r] = 1.0f / l_run[r];
#pragma unroll
  for (int o = 0; o < 8; o++)
#pragma unroll
    for (int r = 0; r < 4; r++) {
      int row = q0 + wave * 16 + quad * 4 + r;
      AO[((size_t)(b * S_ + row) * D_) + h * HD_ + o * 16 + l16] = f2b(O[o][r] * l_run[r]);
    }
}

extern "C" void kernel_launch(void* const* d_in, const int* in_sizes, int n_in,
                              void* d_out, int out_size, void* d_ws, size_t ws_size,
                              hipStream_t stream) {
  const float* hs    = (const float*)d_in[0];
  const int*   amask = (const int*)d_in[1];
  const float* Wq    = (const float*)d_in[2];
  const float* Wk    = (const float*)d_in[3];
  const float* Wv    = (const float*)d_in[4];
  const float* Wo    = (const float*)d_in[5];
  const float* bo    = (const float*)d_in[6];
  float* out = (float*)d_out;

  // workspace layout (176 MB total); hsHi reused as AO after V-GEMM.
  char* p = (char*)d_ws;
  ushort_t* hsHi = (ushort_t*)p; p += (size_t)16 << 20;
  ushort_t* hsLo = (ushort_t*)p; p += (size_t)16 << 20;
  ushort_t* WqTh = (ushort_t*)p; p += (size_t)8 << 20;
  ushort_t* WqTl = (ushort_t*)p; p += (size_t)8 << 20;
  ushort_t* WkTh = (ushort_t*)p; p += (size_t)8 << 20;
  ushort_t* WkTl = (ushort_t*)p; p += (size_t)8 << 20;
  ushort_t* WvTh = (ushort_t*)p; p += (size_t)8 << 20;
  ushort_t* WoTh = (ushort_t*)p; p += (size_t)8 << 20;
  ushort_t* Qhb  = (ushort_t*)p; p += (size_t)16 << 20;
  ushort_t* Qlb  = (ushort_t*)p; p += (size_t)16 << 20;
  ushort_t* Khb  = (ushort_t*)p; p += (size_t)16 << 20;
  ushort_t* Klb  = (ushort_t*)p; p += (size_t)16 << 20;
  ushort_t* Vb   = (ushort_t*)p; p += (size_t)16 << 20;
  ushort_t* Vt   = (ushort_t*)p; p += (size_t)16 << 20;

  k_split<<<M_ * D_ / 1024, 256, 0, stream>>>(hs, hsHi, hsLo, M_ * D_);
  dim3 tb(32, 8), tg4(D_ / 32, D_ / 32, 4);
  k_transpose4<<<tg4, tb, 0, stream>>>(Wq, Wk, Wv, Wo, WqTh, WqTl, WkTh, WkTl, WvTh, WoTh);

  dim3 gg(D_ / 128, M_ / 128);  // (16, 32)
  k_gemm<true, 1><<<gg, 256, 0, stream>>>(hsHi, hsLo, WqTh, WqTl, Qhb, Qlb, nullptr, nullptr, M_, D_, D_);
  k_gemm<true, 1><<<gg, 256, 0, stream>>>(hsHi, hsLo, WkTh, WkTl, Khb, Klb, nullptr, nullptr, M_, D_, D_);
  k_gemm<false, 0><<<gg, 256, 0, stream>>>(hsHi, nullptr, WvTh, nullptr, Vb, nullptr, nullptr, nullptr, M_, D_, D_);

  dim3 vg(D_ / 32, S_ / 32, B_);
  k_vtrans<<<vg, tb, 0, stream>>>(Vb, Vt);

  dim3 ag(S_ / 64, H_, B_);  // (32, 16, 2)
  k_fattn<<<ag, 256, 0, stream>>>(Qhb, Qlb, Khb, Klb, Vt, amask, hsHi /*AO*/);

  k_gemm<false, 2><<<gg, 256, 0, stream>>>(hsHi /*AO*/, nullptr, WoTh, nullptr, nullptr, nullptr, out, bo, M_, D_, D_);
}

// Round 8
// 526.347 us; speedup vs baseline: 1.0323x; 1.0323x over previous
//
#include <hip/hip_runtime.h>

#define B_   2
#define S_   2048
#define D_   2048
#define H_   16
#define HD_  128
#define WIN_ 256
#define M_   (B_ * S_)  // 4096

typedef float  f32x4  __attribute__((ext_vector_type(4)));
typedef short  s16x8  __attribute__((ext_vector_type(8)));
typedef __bf16 bf16x8 __attribute__((ext_vector_type(8)));
typedef unsigned short ushort_t;

__device__ inline unsigned short f2b(float f) {
  unsigned u = __builtin_bit_cast(unsigned, f);
  u += 0x7fffu + ((u >> 16) & 1u);  // RNE
  return (unsigned short)(u >> 16);
}
__device__ inline float b2f(unsigned short h) {
  unsigned u = ((unsigned)h) << 16;
  return __builtin_bit_cast(float, u);
}

// Hedged MFMA call: gfx950 builtin may take v8bf16 (upstream clang) or v8i16.
template <typename T>
__device__ auto mfma_impl(T a, T b, f32x4 c, int)
    -> decltype(__builtin_amdgcn_mfma_f32_16x16x32_bf16(a, b, c, 0, 0, 0)) {
  return __builtin_amdgcn_mfma_f32_16x16x32_bf16(a, b, c, 0, 0, 0);
}
template <typename T>
__device__ f32x4 mfma_impl(T a, T b, f32x4 c, long) {
  return __builtin_amdgcn_mfma_f32_16x16x32_bf16(
      __builtin_bit_cast(bf16x8, a), __builtin_bit_cast(bf16x8, b), c, 0, 0, 0);
}
__device__ inline f32x4 mfma_bf16(s16x8 a, s16x8 b, f32x4 c) {
  return mfma_impl(a, b, c, 0);
}

// ---- async global->LDS, 16B/lane. lds base must be wave-uniform; lane i lands at +i*16B.
#if defined(__has_builtin)
#if __has_builtin(__builtin_amdgcn_global_load_lds)
#define HAS_GLL 1
#endif
#endif
#ifndef HAS_GLL
#define HAS_GLL 0
#endif

__device__ inline void gl_lds16(const ushort_t* g, ushort_t* lds_wave_base) {
#if HAS_GLL
  __builtin_amdgcn_global_load_lds(
      (const __attribute__((address_space(1))) unsigned int*)g,
      (__attribute__((address_space(3))) unsigned int*)lds_wave_base, 16, 0, 0);
#else
  const int lane = threadIdx.x & 63;
  *(uint4*)(lds_wave_base + lane * 8) = *(const uint4*)g;
#endif
}

// ---------------- split f32 -> bf16 hi + lo ----------------
__global__ __launch_bounds__(256) void k_split(const float* __restrict__ x,
                                               ushort_t* __restrict__ hi,
                                               ushort_t* __restrict__ lo, int n) {
  int i = (blockIdx.x * 256 + threadIdx.x) * 4;
  if (i + 3 < n) {
    float4 v = *(const float4*)(x + i);
    ushort4 h, l;
    h.x = f2b(v.x); l.x = f2b(v.x - b2f(h.x));
    h.y = f2b(v.y); l.y = f2b(v.y - b2f(h.y));
    h.z = f2b(v.z); l.z = f2b(v.z - b2f(h.z));
    h.w = f2b(v.w); l.w = f2b(v.w - b2f(h.w));
    *(ushort4*)(hi + i) = h;
    *(ushort4*)(lo + i) = l;
  }
}

// ---------------- fused transpose + split of all 4 weights: z picks W ----------------
// WT[n][k] = W[k][n]; lo written only where needed (Wq, Wk).
__global__ __launch_bounds__(256) void k_transpose4(const float* __restrict__ W0,
                                                    const float* __restrict__ W1,
                                                    const float* __restrict__ W2,
                                                    const float* __restrict__ W3,
                                                    ushort_t* __restrict__ T0h,
                                                    ushort_t* __restrict__ T0l,
                                                    ushort_t* __restrict__ T1h,
                                                    ushort_t* __restrict__ T1l,
                                                    ushort_t* __restrict__ T2h,
                                                    ushort_t* __restrict__ T3h) {
  __shared__ float t[32][33];
  const int z = blockIdx.z;
  const float* W = (z == 0) ? W0 : (z == 1) ? W1 : (z == 2) ? W2 : W3;
  ushort_t* Th = (z == 0) ? T0h : (z == 1) ? T1h : (z == 2) ? T2h : T3h;
  ushort_t* Tl = (z == 0) ? T0l : (z == 1) ? T1l : nullptr;
  int bx = blockIdx.x * 32, by = blockIdx.y * 32;
  int tx = threadIdx.x, ty = threadIdx.y;  // 32 x 8
#pragma unroll
  for (int r = 0; r < 32; r += 8)
    t[ty + r][tx] = W[(size_t)(by + ty + r) * D_ + bx + tx];
  __syncthreads();
#pragma unroll
  for (int r = 0; r < 32; r += 8) {
    float v = t[tx][ty + r];
    unsigned short h = f2b(v);
    Th[(size_t)(bx + ty + r) * D_ + by + tx] = h;
    if (Tl) Tl[(size_t)(bx + ty + r) * D_ + by + tx] = f2b(v - b2f(h));
  }
}

// ---------------- bf16 transpose for V: Vt[b*D + c][s] = Vb[b*S + s][c] ----------------
__global__ __launch_bounds__(256) void k_vtrans(const ushort_t* __restrict__ Vb,
                                                ushort_t* __restrict__ Vt) {
  __shared__ ushort_t t[32][33];
  int bx = blockIdx.x * 32, by = blockIdx.y * 32, b = blockIdx.z;
  int tx = threadIdx.x, ty = threadIdx.y;  // 32 x 8
#pragma unroll
  for (int r = 0; r < 32; r += 8)
    t[ty + r][tx] = Vb[((size_t)(b * S_ + by + ty + r)) * D_ + bx + tx];
  __syncthreads();
#pragma unroll
  for (int r = 0; r < 32; r += 8)
    Vt[((size_t)(b * D_ + bx + ty + r)) * S_ + by + tx] = t[tx][ty + r];
}

// ---------------- m97-structure MFMA GEMM: C = A[MxK] * Bt[NxK]^T ----------------
// 128x128 tile, BK=32, global_load_lds width-16 staging, 4 waves 2x2, 4x4 acc/wave.
// SPLIT3: A,B have hi/lo pairs, 3 MFMAs (hh,hl,lh). OUT: 0=bf16, 1=bf16 hi/lo, 2=f32+bias.
template <bool SPLIT3, int OUT>
__global__ __launch_bounds__(256) void k_gemm(const ushort_t* __restrict__ Ah,
                                              const ushort_t* __restrict__ Al,
                                              const ushort_t* __restrict__ Bh,
                                              const ushort_t* __restrict__ Bl,
                                              ushort_t* __restrict__ Co,
                                              ushort_t* __restrict__ Col,
                                              float* __restrict__ Cf,
                                              const float* __restrict__ bias,
                                              int M, int N, int K) {
  constexpr int NB = SPLIT3 ? 2 : 1;
  __shared__ ushort_t Ash[NB][128][32];  // unpadded: layout forced by global_load_lds
  __shared__ ushort_t Bsh[NB][128][32];
  const int tid = threadIdx.x;
  const int wave = tid >> 6, lane = tid & 63;
  const int m0 = blockIdx.y * 128, n0 = blockIdx.x * 128;
  const int wr = (wave >> 1) * 64, wc = (wave & 1) * 64;
  const int quad = lane >> 4, l16 = lane & 15;
  const int srow = tid >> 2, scol = (tid & 3) * 8;
  const size_t aoff = (size_t)(m0 + srow) * K + scol;
  const size_t boff = (size_t)(n0 + srow) * K + scol;
  const int wofs = wave * 512;  // ushort offset of this wave's 1KB chunk

  f32x4 acc[4][4] = {};
  for (int k0 = 0; k0 < K; k0 += 32) {
#pragma unroll
    for (int s = 0; s < NB; s++) {
      const ushort_t* Asrc = (SPLIT3 && s) ? (Al + aoff + k0) : (Ah + aoff + k0);
      const ushort_t* Bsrc = (SPLIT3 && s) ? (Bl + boff + k0) : (Bh + boff + k0);
      gl_lds16(Asrc,                 &Ash[s][0][0] + wofs);
      gl_lds16(Asrc + (size_t)64 * K, &Ash[s][64][0] + wofs);
      gl_lds16(Bsrc,                 &Bsh[s][0][0] + wofs);
      gl_lds16(Bsrc + (size_t)64 * K, &Bsh[s][64][0] + wofs);
    }
    __syncthreads();
    s16x8 bf[NB][4];
#pragma unroll
    for (int s = 0; s < NB; s++)
#pragma unroll
      for (int jt = 0; jt < 4; jt++)
        bf[s][jt] = *(const s16x8*)&Bsh[s][wc + jt * 16 + l16][quad * 8];
#pragma unroll
    for (int it = 0; it < 4; it++) {
      s16x8 ah = *(const s16x8*)&Ash[0][wr + it * 16 + l16][quad * 8];
      s16x8 al;
      if (SPLIT3) al = *(const s16x8*)&Ash[NB - 1][wr + it * 16 + l16][quad * 8];
#pragma unroll
      for (int jt = 0; jt < 4; jt++) {
        acc[it][jt] = mfma_bf16(ah, bf[0][jt], acc[it][jt]);
        if (SPLIT3) {
          acc[it][jt] = mfma_bf16(ah, bf[NB - 1][jt], acc[it][jt]);
          acc[it][jt] = mfma_bf16(al, bf[0][jt], acc[it][jt]);
        }
      }
    }
    __syncthreads();
  }
#pragma unroll
  for (int it = 0; it < 4; it++)
#pragma unroll
    for (int jt = 0; jt < 4; jt++)
#pragma unroll
      for (int r = 0; r < 4; r++) {
        int row = m0 + wr + it * 16 + quad * 4 + r;
        int col = n0 + wc + jt * 16 + l16;
        float v = acc[it][jt][r];
        if (OUT == 2) {
          Cf[(size_t)row * N + col] = v + bias[col];
        } else if (OUT == 1) {
          unsigned short h = f2b(v);
          Co[(size_t)row * N + col]  = h;
          Col[(size_t)row * N + col] = f2b(v - b2f(h));
        } else {
          Co[(size_t)row * N + col] = f2b(v);
        }
      }
}

// ---------------- MFMA flash attention, 64-query tile per block ----------------
// Scores: split-2 bf16 QK^T: s = (qh+ql)·kh  (K-lo dropped; error ~0.015 on scores).
// P,V: plain bf16. Online softmax. R3-proven barrier structure — do not touch.
// grid: (S/64, H, B); 256 threads = 4 waves, wave w owns queries w*16..w*16+15.
__global__ __launch_bounds__(256) void k_fattn(const ushort_t* __restrict__ Qh,
                                               const ushort_t* __restrict__ Ql,
                                               const ushort_t* __restrict__ Kh,
                                               const ushort_t* __restrict__ Vt,
                                               const int* __restrict__ amask,
                                               ushort_t* __restrict__ AO) {
  __shared__ ushort_t Ksh[64][136];   // [key][dim], +8 pad (17.4 KB)
  __shared__ ushort_t Vs[128][72];    // [hd][key], +8 pad (18.4 KB)
  __shared__ ushort_t ps[4][16][72];  // per-wave P scratch [q][key] (9.2 KB)
  __shared__ int ams[320];            // total ~46.3 KB -> 3 blocks/CU
  const int tid = threadIdx.x;
  const int wave = tid >> 6, lane = tid & 63;
  const int quad = lane >> 4, l16 = lane & 15;
  const int qt = blockIdx.x, h = blockIdx.y, b = blockIdx.z;
  const int q0 = qt * 64;

  for (int x = tid; x < 320; x += 256) {
    int j = q0 - 256 + x;
    ams[x] = (j >= 0) ? amask[b * S_ + j] : 0;
  }

  const int qrowA = q0 + wave * 16 + l16;
  const ushort_t* qbh = Qh + ((size_t)(b * S_ + qrowA) * D_) + h * HD_;
  const ushort_t* qbl = Ql + ((size_t)(b * S_ + qrowA) * D_) + h * HD_;
  s16x8 qh[4], ql[4];
#pragma unroll
  for (int kk = 0; kk < 4; kk++) {
    qh[kk] = *(const s16x8*)(qbh + kk * 32 + quad * 8);
    ql[kk] = *(const s16x8*)(qbl + kk * 32 + quad * 8);
  }

  f32x4 O[8] = {};
  float m_run[4], l_run[4];
#pragma unroll
  for (int r = 0; r < 4; r++) { m_run[r] = -3.0e38f; l_run[r] = 0.f; }

  const int t0 = (qt < 4) ? (4 - qt) : 0;  // kb = 64*(qt+t-4) >= 0
  for (int t = t0; t < 5; t++) {
    const int kb = q0 - 256 + 64 * t;
    __syncthreads();
    // stage K tile (hi only): [key][dim]; thread: key=tid>>2, dims (tid&3)*32..+31
    {
      const int key = tid >> 2, dimb = (tid & 3) * 32;
      const ushort_t* kgh = Kh + ((size_t)(b * S_ + kb + key) * D_) + h * HD_ + dimb;
#pragma unroll
      for (int u = 0; u < 4; u++)
        *(uint4*)&Ksh[key][dimb + u * 8] = *(const uint4*)(kgh + u * 8);
      // stage V tile (pre-transposed): Vs[hd][key]; thread: hd=tid>>1, keys (tid&1)*32..+31
      const int hd = tid >> 1, keyb = (tid & 1) * 32;
      const ushort_t* vg = Vt + ((size_t)(b * D_ + h * HD_ + hd) * S_) + kb + keyb;
#pragma unroll
      for (int u = 0; u < 4; u++)
        *(uint4*)&Vs[hd][keyb + u * 8] = *(const uint4*)(vg + u * 8);
    }
    __syncthreads();

    f32x4 sacc[4] = {};
#pragma unroll
    for (int kk = 0; kk < 4; kk++)
#pragma unroll
      for (int nt = 0; nt < 4; nt++) {
        s16x8 kfh = *(const s16x8*)&Ksh[nt * 16 + l16][kk * 32 + quad * 8];
        sacc[nt] = mfma_bf16(qh[kk], kfh, sacc[nt]);
        sacc[nt] = mfma_bf16(ql[kk], kfh, sacc[nt]);
      }

#pragma unroll
    for (int nt = 0; nt < 4; nt++) {
      const int j = kb + nt * 16 + l16;
      const bool amok = ams[64 * t + nt * 16 + l16] != 0;
#pragma unroll
      for (int r = 0; r < 4; r++) {
        const int iq = q0 + wave * 16 + quad * 4 + r;
        const bool ok = amok && (j <= iq) && (j > iq - WIN_);
        if (!ok) sacc[nt][r] = -3.0e38f;
      }
    }
    float mt[4];
#pragma unroll
    for (int r = 0; r < 4; r++) {
      mt[r] = fmaxf(fmaxf(sacc[0][r], sacc[1][r]), fmaxf(sacc[2][r], sacc[3][r]));
      mt[r] = fmaxf(mt[r], __shfl_xor(mt[r], 1));
      mt[r] = fmaxf(mt[r], __shfl_xor(mt[r], 2));
      mt[r] = fmaxf(mt[r], __shfl_xor(mt[r], 4));
      mt[r] = fmaxf(mt[r], __shfl_xor(mt[r], 8));
    }
    float alpha[4], lt[4];
#pragma unroll
    for (int r = 0; r < 4; r++) {
      float mnew = fmaxf(m_run[r], mt[r]);
      alpha[r] = __expf(m_run[r] - mnew);
      m_run[r] = mnew;
      lt[r] = 0.f;
#pragma unroll
      for (int nt = 0; nt < 4; nt++) {
        float s = sacc[nt][r];
        float p = (s > -1.0e30f) ? __expf(s - mnew) : 0.f;
        sacc[nt][r] = p;
        lt[r] += p;
      }
      lt[r] += __shfl_xor(lt[r], 1);
      lt[r] += __shfl_xor(lt[r], 2);
      lt[r] += __shfl_xor(lt[r], 4);
      lt[r] += __shfl_xor(lt[r], 8);
      l_run[r] = l_run[r] * alpha[r] + lt[r];
    }
#pragma unroll
    for (int o = 0; o < 8; o++)
#pragma unroll
      for (int r = 0; r < 4; r++) O[o][r] *= alpha[r];
#pragma unroll
    for (int nt = 0; nt < 4; nt++)
#pragma unroll
      for (int r = 0; r < 4; r++)
        ps[wave][quad * 4 + r][nt * 16 + l16] = f2b(sacc[nt][r]);
    __syncthreads();
#pragma unroll
    for (int kk2 = 0; kk2 < 2; kk2++) {
      s16x8 pf = *(const s16x8*)&ps[wave][l16][kk2 * 32 + quad * 8];
#pragma unroll
      for (int o = 0; o < 8; o++) {
        s16x8 vf = *(const s16x8*)&Vs[o * 16 + l16][kk2 * 32 + quad * 8];
        O[o] = mfma_bf16(pf, vf, O[o]);
      }
    }
  }
#pragma unroll
  for (int r = 0; r < 4; r++) l_run[r] = 1.0f / l_run[r];
#pragma unroll
  for (int o = 0; o < 8; o++)
#pragma unroll
    for (int r = 0; r < 4; r++) {
      int row = q0 + wave * 16 + quad * 4 + r;
      AO[((size_t)(b * S_ + row) * D_) + h * HD_ + o * 16 + l16] = f2b(O[o][r] * l_run[r]);
    }
}

extern "C" void kernel_launch(void* const* d_in, const int* in_sizes, int n_in,
                              void* d_out, int out_size, void* d_ws, size_t ws_size,
                              hipStream_t stream) {
  const float* hs    = (const float*)d_in[0];
  const int*   amask = (const int*)d_in[1];
  const float* Wq    = (const float*)d_in[2];
  const float* Wk    = (const float*)d_in[3];
  const float* Wv    = (const float*)d_in[4];
  const float* Wo    = (const float*)d_in[5];
  const float* bo    = (const float*)d_in[6];
  float* out = (float*)d_out;

  // workspace layout; hsHi reused as AO after V-GEMM. (Klb slot retired.)
  char* p = (char*)d_ws;
  ushort_t* hsHi = (ushort_t*)p; p += (size_t)16 << 20;
  ushort_t* hsLo = (ushort_t*)p; p += (size_t)16 << 20;
  ushort_t* WqTh = (ushort_t*)p; p += (size_t)8 << 20;
  ushort_t* WqTl = (ushort_t*)p; p += (size_t)8 << 20;
  ushort_t* WkTh = (ushort_t*)p; p += (size_t)8 << 20;
  ushort_t* WkTl = (ushort_t*)p; p += (size_t)8 << 20;
  ushort_t* WvTh = (ushort_t*)p; p += (size_t)8 << 20;
  ushort_t* WoTh = (ushort_t*)p; p += (size_t)8 << 20;
  ushort_t* Qhb  = (ushort_t*)p; p += (size_t)16 << 20;
  ushort_t* Qlb  = (ushort_t*)p; p += (size_t)16 << 20;
  ushort_t* Khb  = (ushort_t*)p; p += (size_t)16 << 20;
  ushort_t* Vb   = (ushort_t*)p; p += (size_t)16 << 20;
  ushort_t* Vt   = (ushort_t*)p; p += (size_t)16 << 20;

  k_split<<<M_ * D_ / 1024, 256, 0, stream>>>(hs, hsHi, hsLo, M_ * D_);
  dim3 tb(32, 8), tg4(D_ / 32, D_ / 32, 4);
  k_transpose4<<<tg4, tb, 0, stream>>>(Wq, Wk, Wv, Wo, WqTh, WqTl, WkTh, WkTl, WvTh, WoTh);

  dim3 gg(D_ / 128, M_ / 128);  // (16, 32)
  k_gemm<true, 1><<<gg, 256, 0, stream>>>(hsHi, hsLo, WqTh, WqTl, Qhb, Qlb, nullptr, nullptr, M_, D_, D_);
  k_gemm<true, 0><<<gg, 256, 0, stream>>>(hsHi, hsLo, WkTh, WkTl, Khb, nullptr, nullptr, nullptr, M_, D_, D_);
  k_gemm<false, 0><<<gg, 256, 0, stream>>>(hsHi, nullptr, WvTh, nullptr, Vb, nullptr, nullptr, nullptr, M_, D_, D_);

  dim3 vg(D_ / 32, S_ / 32, B_);
  k_vtrans<<<vg, tb, 0, stream>>>(Vb, Vt);

  dim3 ag(S_ / 64, H_, B_);  // (32, 16, 2)
  k_fattn<<<ag, 256, 0, stream>>>(Qhb, Qlb, Khb, Vt, amask, hsHi /*AO*/);

  k_gemm<false, 2><<<gg, 256, 0, stream>>>(hsHi /*AO*/, nullptr, WoTh, nullptr, nullptr, nullptr, out, bo, M_, D_, D_);
}

// Round 9
// 497.750 us; speedup vs baseline: 1.0916x; 1.0575x over previous
//
#include <hip/hip_runtime.h>

#define B_   2
#define S_   2048
#define D_   2048
#define H_   16
#define HD_  128
#define WIN_ 256
#define M_   (B_ * S_)  // 4096

typedef float  f32x4  __attribute__((ext_vector_type(4)));
typedef short  s16x8  __attribute__((ext_vector_type(8)));
typedef __bf16 bf16x8 __attribute__((ext_vector_type(8)));
typedef unsigned short ushort_t;

__device__ inline unsigned short f2b(float f) {
  unsigned u = __builtin_bit_cast(unsigned, f);
  u += 0x7fffu + ((u >> 16) & 1u);  // RNE
  return (unsigned short)(u >> 16);
}
__device__ inline float b2f(unsigned short h) {
  unsigned u = ((unsigned)h) << 16;
  return __builtin_bit_cast(float, u);
}

// Hedged MFMA call: gfx950 builtin may take v8bf16 (upstream clang) or v8i16.
template <typename T>
__device__ auto mfma_impl(T a, T b, f32x4 c, int)
    -> decltype(__builtin_amdgcn_mfma_f32_16x16x32_bf16(a, b, c, 0, 0, 0)) {
  return __builtin_amdgcn_mfma_f32_16x16x32_bf16(a, b, c, 0, 0, 0);
}
template <typename T>
__device__ f32x4 mfma_impl(T a, T b, f32x4 c, long) {
  return __builtin_amdgcn_mfma_f32_16x16x32_bf16(
      __builtin_bit_cast(bf16x8, a), __builtin_bit_cast(bf16x8, b), c, 0, 0, 0);
}
__device__ inline f32x4 mfma_bf16(s16x8 a, s16x8 b, f32x4 c) {
  return mfma_impl(a, b, c, 0);
}

// ---- async global->LDS, 16B/lane. lds base must be wave-uniform; lane i lands at +i*16B.
#if defined(__has_builtin)
#if __has_builtin(__builtin_amdgcn_global_load_lds)
#define HAS_GLL 1
#endif
#endif
#ifndef HAS_GLL
#define HAS_GLL 0
#endif

__device__ inline void gl_lds16(const ushort_t* g, ushort_t* lds_wave_base) {
#if HAS_GLL
  __builtin_amdgcn_global_load_lds(
      (const __attribute__((address_space(1))) unsigned int*)g,
      (__attribute__((address_space(3))) unsigned int*)lds_wave_base, 16, 0, 0);
#else
  const int lane = threadIdx.x & 63;
  *(uint4*)(lds_wave_base + lane * 8) = *(const uint4*)g;
#endif
}

// ---------------- split f32 -> bf16 hi + lo ----------------
__global__ __launch_bounds__(256) void k_split(const float* __restrict__ x,
                                               ushort_t* __restrict__ hi,
                                               ushort_t* __restrict__ lo, int n) {
  int i = (blockIdx.x * 256 + threadIdx.x) * 4;
  if (i + 3 < n) {
    float4 v = *(const float4*)(x + i);
    ushort4 h, l;
    h.x = f2b(v.x); l.x = f2b(v.x - b2f(h.x));
    h.y = f2b(v.y); l.y = f2b(v.y - b2f(h.y));
    h.z = f2b(v.z); l.z = f2b(v.z - b2f(h.z));
    h.w = f2b(v.w); l.w = f2b(v.w - b2f(h.w));
    *(ushort4*)(hi + i) = h;
    *(ushort4*)(lo + i) = l;
  }
}

// ---------------- fused transpose + split of all 4 weights: z picks W ----------------
// WT[n][k] = W[k][n]; lo written only where needed (Wq only, after K went split-2).
__global__ __launch_bounds__(256) void k_transpose4(const float* __restrict__ W0,
                                                    const float* __restrict__ W1,
                                                    const float* __restrict__ W2,
                                                    const float* __restrict__ W3,
                                                    ushort_t* __restrict__ T0h,
                                                    ushort_t* __restrict__ T0l,
                                                    ushort_t* __restrict__ T1h,
                                                    ushort_t* __restrict__ T1l,
                                                    ushort_t* __restrict__ T2h,
                                                    ushort_t* __restrict__ T3h) {
  __shared__ float t[32][33];
  const int z = blockIdx.z;
  const float* W = (z == 0) ? W0 : (z == 1) ? W1 : (z == 2) ? W2 : W3;
  ushort_t* Th = (z == 0) ? T0h : (z == 1) ? T1h : (z == 2) ? T2h : T3h;
  ushort_t* Tl = (z == 0) ? T0l : (z == 1) ? T1l : nullptr;
  int bx = blockIdx.x * 32, by = blockIdx.y * 32;
  int tx = threadIdx.x, ty = threadIdx.y;  // 32 x 8
#pragma unroll
  for (int r = 0; r < 32; r += 8)
    t[ty + r][tx] = W[(size_t)(by + ty + r) * D_ + bx + tx];
  __syncthreads();
#pragma unroll
  for (int r = 0; r < 32; r += 8) {
    float v = t[tx][ty + r];
    unsigned short h = f2b(v);
    Th[(size_t)(bx + ty + r) * D_ + by + tx] = h;
    if (Tl) Tl[(size_t)(bx + ty + r) * D_ + by + tx] = f2b(v - b2f(h));
  }
}

// ---------------- bf16 transpose for V: Vt[b*D + c][s] = Vb[b*S + s][c] ----------------
__global__ __launch_bounds__(256) void k_vtrans(const ushort_t* __restrict__ Vb,
                                                ushort_t* __restrict__ Vt) {
  __shared__ ushort_t t[32][33];
  int bx = blockIdx.x * 32, by = blockIdx.y * 32, b = blockIdx.z;
  int tx = threadIdx.x, ty = threadIdx.y;  // 32 x 8
#pragma unroll
  for (int r = 0; r < 32; r += 8)
    t[ty + r][tx] = Vb[((size_t)(b * S_ + by + ty + r)) * D_ + bx + tx];
  __syncthreads();
#pragma unroll
  for (int r = 0; r < 32; r += 8)
    Vt[((size_t)(b * D_ + bx + ty + r)) * S_ + by + tx] = t[tx][ty + r];
}

// ---------------- m97-structure MFMA GEMM: C = A[MxK] * Bt[NxK]^T ----------------
// 128x128 tile, BK=32, global_load_lds width-16 staging, 4 waves 2x2, 4x4 acc/wave.
// SPLIT: 1 = plain (Ah·Bh); 2 = A-split ((Ah+Al)·Bh); 3 = full (hh + hl + lh).
// OUT: 0=bf16, 1=bf16 hi/lo, 2=f32+bias.
template <int SPLIT, int OUT>
__global__ __launch_bounds__(256) void k_gemm(const ushort_t* __restrict__ Ah,
                                              const ushort_t* __restrict__ Al,
                                              const ushort_t* __restrict__ Bh,
                                              const ushort_t* __restrict__ Bl,
                                              ushort_t* __restrict__ Co,
                                              ushort_t* __restrict__ Col,
                                              float* __restrict__ Cf,
                                              const float* __restrict__ bias,
                                              int M, int N, int K) {
  constexpr int NA = (SPLIT >= 2) ? 2 : 1;
  constexpr int NBB = (SPLIT == 3) ? 2 : 1;
  __shared__ ushort_t Ash[NA][128][32];   // unpadded: layout forced by global_load_lds
  __shared__ ushort_t Bsh[NBB][128][32];
  const int tid = threadIdx.x;
  const int wave = tid >> 6, lane = tid & 63;
  const int m0 = blockIdx.y * 128, n0 = blockIdx.x * 128;
  const int wr = (wave >> 1) * 64, wc = (wave & 1) * 64;
  const int quad = lane >> 4, l16 = lane & 15;
  const int srow = tid >> 2, scol = (tid & 3) * 8;
  const size_t aoff = (size_t)(m0 + srow) * K + scol;
  const size_t boff = (size_t)(n0 + srow) * K + scol;
  const int wofs = wave * 512;  // ushort offset of this wave's 1KB chunk

  f32x4 acc[4][4] = {};
  for (int k0 = 0; k0 < K; k0 += 32) {
    gl_lds16(Ah + aoff + k0,                  &Ash[0][0][0] + wofs);
    gl_lds16(Ah + aoff + k0 + (size_t)64 * K, &Ash[0][64][0] + wofs);
    if (SPLIT >= 2) {
      gl_lds16(Al + aoff + k0,                  &Ash[NA - 1][0][0] + wofs);
      gl_lds16(Al + aoff + k0 + (size_t)64 * K, &Ash[NA - 1][64][0] + wofs);
    }
    gl_lds16(Bh + boff + k0,                  &Bsh[0][0][0] + wofs);
    gl_lds16(Bh + boff + k0 + (size_t)64 * K, &Bsh[0][64][0] + wofs);
    if (SPLIT == 3) {
      gl_lds16(Bl + boff + k0,                  &Bsh[NBB - 1][0][0] + wofs);
      gl_lds16(Bl + boff + k0 + (size_t)64 * K, &Bsh[NBB - 1][64][0] + wofs);
    }
    __syncthreads();
    s16x8 bf[NBB][4];
#pragma unroll
    for (int s = 0; s < NBB; s++)
#pragma unroll
      for (int jt = 0; jt < 4; jt++)
        bf[s][jt] = *(const s16x8*)&Bsh[s][wc + jt * 16 + l16][quad * 8];
#pragma unroll
    for (int it = 0; it < 4; it++) {
      s16x8 ah = *(const s16x8*)&Ash[0][wr + it * 16 + l16][quad * 8];
      s16x8 al;
      if (SPLIT >= 2) al = *(const s16x8*)&Ash[NA - 1][wr + it * 16 + l16][quad * 8];
#pragma unroll
      for (int jt = 0; jt < 4; jt++) {
        acc[it][jt] = mfma_bf16(ah, bf[0][jt], acc[it][jt]);
        if (SPLIT == 3)
          acc[it][jt] = mfma_bf16(ah, bf[NBB - 1][jt], acc[it][jt]);
        if (SPLIT >= 2)
          acc[it][jt] = mfma_bf16(al, bf[0][jt], acc[it][jt]);
      }
    }
    __syncthreads();
  }
#pragma unroll
  for (int it = 0; it < 4; it++)
#pragma unroll
    for (int jt = 0; jt < 4; jt++)
#pragma unroll
      for (int r = 0; r < 4; r++) {
        int row = m0 + wr + it * 16 + quad * 4 + r;
        int col = n0 + wc + jt * 16 + l16;
        float v = acc[it][jt][r];
        if (OUT == 2) {
          Cf[(size_t)row * N + col] = v + bias[col];
        } else if (OUT == 1) {
          unsigned short h = f2b(v);
          Co[(size_t)row * N + col]  = h;
          Col[(size_t)row * N + col] = f2b(v - b2f(h));
        } else {
          Co[(size_t)row * N + col] = f2b(v);
        }
      }
}

// ---------------- MFMA flash attention, 64-query tile per block ----------------
// Scores: split-2 bf16 QK^T: s = (qh+ql)·kh  (K-lo dropped; error ~0.02 on scores).
// P,V: plain bf16. Online softmax. R3-proven barrier structure — do not touch.
// grid: (S/64, H, B); 256 threads = 4 waves, wave w owns queries w*16..w*16+15.
__global__ __launch_bounds__(256) void k_fattn(const ushort_t* __restrict__ Qh,
                                               const ushort_t* __restrict__ Ql,
                                               const ushort_t* __restrict__ Kh,
                                               const ushort_t* __restrict__ Vt,
                                               const int* __restrict__ amask,
                                               ushort_t* __restrict__ AO) {
  __shared__ ushort_t Ksh[64][136];   // [key][dim], +8 pad (17.4 KB)
  __shared__ ushort_t Vs[128][72];    // [hd][key], +8 pad (18.4 KB)
  __shared__ ushort_t ps[4][16][72];  // per-wave P scratch [q][key] (9.2 KB)
  __shared__ int ams[320];            // total ~46.3 KB -> 3 blocks/CU
  const int tid = threadIdx.x;
  const int wave = tid >> 6, lane = tid & 63;
  const int quad = lane >> 4, l16 = lane & 15;
  const int qt = blockIdx.x, h = blockIdx.y, b = blockIdx.z;
  const int q0 = qt * 64;

  for (int x = tid; x < 320; x += 256) {
    int j = q0 - 256 + x;
    ams[x] = (j >= 0) ? amask[b * S_ + j] : 0;
  }

  const int qrowA = q0 + wave * 16 + l16;
  const ushort_t* qbh = Qh + ((size_t)(b * S_ + qrowA) * D_) + h * HD_;
  const ushort_t* qbl = Ql + ((size_t)(b * S_ + qrowA) * D_) + h * HD_;
  s16x8 qh[4], ql[4];
#pragma unroll
  for (int kk = 0; kk < 4; kk++) {
    qh[kk] = *(const s16x8*)(qbh + kk * 32 + quad * 8);
    ql[kk] = *(const s16x8*)(qbl + kk * 32 + quad * 8);
  }

  f32x4 O[8] = {};
  float m_run[4], l_run[4];
#pragma unroll
  for (int r = 0; r < 4; r++) { m_run[r] = -3.0e38f; l_run[r] = 0.f; }

  const int t0 = (qt < 4) ? (4 - qt) : 0;  // kb = 64*(qt+t-4) >= 0
  for (int t = t0; t < 5; t++) {
    const int kb = q0 - 256 + 64 * t;
    __syncthreads();
    // stage K tile (hi only): [key][dim]; thread: key=tid>>2, dims (tid&3)*32..+31
    {
      const int key = tid >> 2, dimb = (tid & 3) * 32;
      const ushort_t* kgh = Kh + ((size_t)(b * S_ + kb + key) * D_) + h * HD_ + dimb;
#pragma unroll
      for (int u = 0; u < 4; u++)
        *(uint4*)&Ksh[key][dimb + u * 8] = *(const uint4*)(kgh + u * 8);
      // stage V tile (pre-transposed): Vs[hd][key]; thread: hd=tid>>1, keys (tid&1)*32..+31
      const int hd = tid >> 1, keyb = (tid & 1) * 32;
      const ushort_t* vg = Vt + ((size_t)(b * D_ + h * HD_ + hd) * S_) + kb + keyb;
#pragma unroll
      for (int u = 0; u < 4; u++)
        *(uint4*)&Vs[hd][keyb + u * 8] = *(const uint4*)(vg + u * 8);
    }
    __syncthreads();

    f32x4 sacc[4] = {};
#pragma unroll
    for (int kk = 0; kk < 4; kk++)
#pragma unroll
      for (int nt = 0; nt < 4; nt++) {
        s16x8 kfh = *(const s16x8*)&Ksh[nt * 16 + l16][kk * 32 + quad * 8];
        sacc[nt] = mfma_bf16(qh[kk], kfh, sacc[nt]);
        sacc[nt] = mfma_bf16(ql[kk], kfh, sacc[nt]);
      }

#pragma unroll
    for (int nt = 0; nt < 4; nt++) {
      const int j = kb + nt * 16 + l16;
      const bool amok = ams[64 * t + nt * 16 + l16] != 0;
#pragma unroll
      for (int r = 0; r < 4; r++) {
        const int iq = q0 + wave * 16 + quad * 4 + r;
        const bool ok = amok && (j <= iq) && (j > iq - WIN_);
        if (!ok) sacc[nt][r] = -3.0e38f;
      }
    }
    float mt[4];
#pragma unroll
    for (int r = 0; r < 4; r++) {
      mt[r] = fmaxf(fmaxf(sacc[0][r], sacc[1][r]), fmaxf(sacc[2][r], sacc[3][r]));
      mt[r] = fmaxf(mt[r], __shfl_xor(mt[r], 1));
      mt[r] = fmaxf(mt[r], __shfl_xor(mt[r], 2));
      mt[r] = fmaxf(mt[r], __shfl_xor(mt[r], 4));
      mt[r] = fmaxf(mt[r], __shfl_xor(mt[r], 8));
    }
    float alpha[4], lt[4];
#pragma unroll
    for (int r = 0; r < 4; r++) {
      float mnew = fmaxf(m_run[r], mt[r]);
      alpha[r] = __expf(m_run[r] - mnew);
      m_run[r] = mnew;
      lt[r] = 0.f;
#pragma unroll
      for (int nt = 0; nt < 4; nt++) {
        float s = sacc[nt][r];
        float p = (s > -1.0e30f) ? __expf(s - mnew) : 0.f;
        sacc[nt][r] = p;
        lt[r] += p;
      }
      lt[r] += __shfl_xor(lt[r], 1);
      lt[r] += __shfl_xor(lt[r], 2);
      lt[r] += __shfl_xor(lt[r], 4);
      lt[r] += __shfl_xor(lt[r], 8);
      l_run[r] = l_run[r] * alpha[r] + lt[r];
    }
#pragma unroll
    for (int o = 0; o < 8; o++)
#pragma unroll
      for (int r = 0; r < 4; r++) O[o][r] *= alpha[r];
#pragma unroll
    for (int nt = 0; nt < 4; nt++)
#pragma unroll
      for (int r = 0; r < 4; r++)
        ps[wave][quad * 4 + r][nt * 16 + l16] = f2b(sacc[nt][r]);
    __syncthreads();
#pragma unroll
    for (int kk2 = 0; kk2 < 2; kk2++) {
      s16x8 pf = *(const s16x8*)&ps[wave][l16][kk2 * 32 + quad * 8];
#pragma unroll
      for (int o = 0; o < 8; o++) {
        s16x8 vf = *(const s16x8*)&Vs[o * 16 + l16][kk2 * 32 + quad * 8];
        O[o] = mfma_bf16(pf, vf, O[o]);
      }
    }
  }
#pragma unroll
  for (int r = 0; r < 4; r++) l_run[r] = 1.0f / l_run[r];
#pragma unroll
  for (int o = 0; o < 8; o++)
#pragma unroll
    for (int r = 0; r < 4; r++) {
      int row = q0 + wave * 16 + quad * 4 + r;
      AO[((size_t)(b * S_ + row) * D_) + h * HD_ + o * 16 + l16] = f2b(O[o][r] * l_run[r]);
    }
}

extern "C" void kernel_launch(void* const* d_in, const int* in_sizes, int n_in,
                              void* d_out, int out_size, void* d_ws, size_t ws_size,
                              hipStream_t stream) {
  const float* hs    = (const float*)d_in[0];
  const int*   amask = (const int*)d_in[1];
  const float* Wq    = (const float*)d_in[2];
  const float* Wk    = (const float*)d_in[3];
  const float* Wv    = (const float*)d_in[4];
  const float* Wo    = (const float*)d_in[5];
  const float* bo    = (const float*)d_in[6];
  float* out = (float*)d_out;

  // workspace layout; hsHi reused as AO after V-GEMM. (WkTl slot retained but unused.)
  char* p = (char*)d_ws;
  ushort_t* hsHi = (ushort_t*)p; p += (size_t)16 << 20;
  ushort_t* hsLo = (ushort_t*)p; p += (size_t)16 << 20;
  ushort_t* WqTh = (ushort_t*)p; p += (size_t)8 << 20;
  ushort_t* WqTl = (ushort_t*)p; p += (size_t)8 << 20;
  ushort_t* WkTh = (ushort_t*)p; p += (size_t)8 << 20;
  ushort_t* WkTl = (ushort_t*)p; p += (size_t)8 << 20;  (void)WkTl;
  ushort_t* WvTh = (ushort_t*)p; p += (size_t)8 << 20;
  ushort_t* WoTh = (ushort_t*)p; p += (size_t)8 << 20;
  ushort_t* Qhb  = (ushort_t*)p; p += (size_t)16 << 20;
  ushort_t* Qlb  = (ushort_t*)p; p += (size_t)16 << 20;
  ushort_t* Khb  = (ushort_t*)p; p += (size_t)16 << 20;
  ushort_t* Vb   = (ushort_t*)p; p += (size_t)16 << 20;
  ushort_t* Vt   = (ushort_t*)p; p += (size_t)16 << 20;

  k_split<<<M_ * D_ / 1024, 256, 0, stream>>>(hs, hsHi, hsLo, M_ * D_);
  dim3 tb(32, 8), tg4(D_ / 32, D_ / 32, 4);
  k_transpose4<<<tg4, tb, 0, stream>>>(Wq, Wk, Wv, Wo, WqTh, WqTl, WkTh, nullptr, WvTh, WoTh);

  dim3 gg(D_ / 128, M_ / 128);  // (16, 32)
  k_gemm<3, 1><<<gg, 256, 0, stream>>>(hsHi, hsLo, WqTh, WqTl, Qhb, Qlb, nullptr, nullptr, M_, D_, D_);
  k_gemm<2, 0><<<gg, 256, 0, stream>>>(hsHi, hsLo, WkTh, nullptr, Khb, nullptr, nullptr, nullptr, M_, D_, D_);
  k_gemm<1, 0><<<gg, 256, 0, stream>>>(hsHi, nullptr, WvTh, nullptr, Vb, nullptr, nullptr, nullptr, M_, D_, D_);

  dim3 vg(D_ / 32, S_ / 32, B_);
  k_vtrans<<<vg, tb, 0, stream>>>(Vb, Vt);

  dim3 ag(S_ / 64, H_, B_);  // (32, 16, 2)
  k_fattn<<<ag, 256, 0, stream>>>(Qhb, Qlb, Khb, Vt, amask, hsHi /*AO*/);

  k_gemm<1, 2><<<gg, 256, 0, stream>>>(hsHi /*AO*/, nullptr, WoTh, nullptr, nullptr, nullptr, out, bo, M_, D_, D_);
}